// Round 8
// baseline (402.559 us; speedup 1.0000x reference)
//
#include <hip/hip_runtime.h>
#include <float.h>

// Problem constants: x (2,128,64,64) fp32, w (256,256) fp32, b (256,) fp32
// out (2,256,64,64) fp32. K=9 nearest neighbors on normalized features.
constexpr int CB = 2;      // batch
constexpr int CC = 128;    // channels
constexpr int CN = 4096;   // points (64*64)
constexpr int CO2 = 512;   // P(256) + Q(256) packed weight columns
constexpr int NSPLIT = 16; // knn col-splits (grid.x)

// ---- workspace layout (float offsets), total ~14.3 MB ----
// PV/PJ overlay the Q region: merge_kernel consumes PV/PJ BEFORE pq_kernel
// writes Q (same stream, serialized) and pq fully overwrites Q each call.
constexpr size_t OFF_XN = 0;                                  // [B][C][N] normalized x
constexpr size_t OFF_SQ = OFF_XN + (size_t)CB * CC * CN;      // [B][N] sum(xn^2)
constexpr size_t OFF_RN = OFF_SQ + (size_t)CB * CN;           // [B][N] norm
constexpr size_t OFF_WT = OFF_RN + (size_t)CB * CN;           // [C][512] (W1-W2 | W2)^T
constexpr size_t OFF_Q  = OFF_WT + (size_t)CC * CO2;          // [B][N][256] Q = W2^T x
constexpr size_t OFF_PV = OFF_Q;                              // [B][N][16][9] vals (overlay)
constexpr size_t OFF_PJ = OFF_PV + (size_t)CB * CN * NSPLIT * 9;
constexpr size_t OFF_NN = OFF_PJ + (size_t)CB * CN * NSPLIT * 9;  // [B][N][9] final idx

// top-9 sorted-desc insert; comparator matches jax.lax.top_k tie-break:
// better == (v > cur) || (v == cur && idx < cur_idx). Order-independent.
__device__ __forceinline__ void topk_insert(float (&sv)[9], int (&sj)[9], float v, int jg) {
    if ((v > sv[8]) || (v == sv[8] && jg < sj[8])) {
        bool bb[9];
#pragma unroll
        for (int k = 0; k < 9; ++k) bb[k] = (v > sv[k]) || (v == sv[k] && jg < sj[k]);
#pragma unroll
        for (int k = 8; k >= 1; --k) {
            sv[k] = bb[k - 1] ? sv[k - 1] : (bb[k] ? v : sv[k]);
            sj[k] = bb[k - 1] ? sj[k - 1] : (bb[k] ? jg : sj[k]);
        }
        sv[0] = bb[0] ? v : sv[0];
        sj[0] = bb[0] ? jg : sj[0];
    }
}

// ---- Kernel A: normalize; xn = x * rsqrt(sum x^2 + eps); sq = sum xn^2; rn = sqrt(ss+eps)
__global__ __launch_bounds__(256) void prep_kernel(const float* __restrict__ x,
                                                   float* __restrict__ xn,
                                                   float* __restrict__ sqv,
                                                   float* __restrict__ rnv) {
    __shared__ float XT[128][64];
    __shared__ float red[4][64];
    __shared__ float invl[64];
    const int b = blockIdx.y, n0 = blockIdx.x * 64;
    const int tid = threadIdx.x;
    const int nl = tid & 63, c0 = tid >> 6;
#pragma unroll 4
    for (int cc = 0; cc < 32; ++cc) {
        int c = cc * 4 + c0;
        XT[c][nl] = x[((size_t)(b * 128 + c)) * 4096 + n0 + nl];
    }
    __syncthreads();
    {
        float acc = 0.f;
#pragma unroll 4
        for (int cc = 0; cc < 32; ++cc) { float v = XT[c0 * 32 + cc][nl]; acc += v * v; }
        red[c0][nl] = acc;
    }
    __syncthreads();
    if (tid < 64) {
        float ss = red[0][tid] + red[1][tid] + red[2][tid] + red[3][tid] + 1e-12f;
        float sr = sqrtf(ss);
        invl[tid] = 1.0f / sr;
        rnv[b * 4096 + n0 + tid] = sr;
    }
    __syncthreads();
    {
        float acc = 0.f;
        float iv = invl[nl];
#pragma unroll 4
        for (int cc = 0; cc < 32; ++cc) {
            int c = cc * 4 + c0;
            float v = XT[c][nl] * iv;
            xn[((size_t)(b * 128 + c)) * 4096 + n0 + nl] = v;
            acc += v * v;
        }
        red[c0][nl] = acc;
    }
    __syncthreads();
    if (tid < 64) {
        sqv[b * 4096 + n0 + tid] = red[0][tid] + red[1][tid] + red[2][tid] + red[3][tid];
    }
}

// ---- Kernel W: WT[c][o] = (o<256) ? w[o][c]-w[o][128+c] : w[o-256][128+c] ----
__global__ __launch_bounds__(256) void wprep_kernel(const float* __restrict__ w,
                                                    float* __restrict__ wt) {
    int id = blockIdx.x * 256 + threadIdx.x;   // 65536 = 128*512
    int c = id >> 9, o = id & 511;
    float v;
    if (o < 256) v = w[o * 256 + c] - w[o * 256 + 128 + c];
    else         v = w[(o - 256) * 256 + 128 + c];
    wt[c * 512 + o] = v;
}

// ---- Kernel B v8: fused Gram + top-9, 4x8 fragments ----
// Tile 64 rows x 128 cols, thread frag 4 rows x (tx*4 | 64+tx*4) cols.
// LDS demand: 48B per c per 32 outputs = 1.5 B/out/c -> LDS-pipe floor ~65us
// (4x4 was 2.0 B/out/c = 109us floor = r7's binder). acc=32 floats avoids the
// 64-float allocator cliff (r3-r5). K-chunk 32, c ascending 0..127 -> scores
// bit-identical to r2/r6/r7. LDS 25.1KB -> 6 blocks/CU; grid 2048 feeds it.
// Full unroll of c-loop -> LDS offsets become immediates (no addr VALU).
__global__ __launch_bounds__(256, 4) void knn_kernel(const float* __restrict__ xn,
                                                     const float* __restrict__ sqv,
                                                     float* __restrict__ pv,
                                                     int* __restrict__ pj) {
    __shared__ float lds[6272];                // 25,088 B
    float* As  = lds;                          // [32][64]  staging
    float* Bs  = lds + 2048;                   // [32][128] staging
    float* Sf  = lds;                          // [32][132] score overlay (4224 f)
    float* SQJ = lds + 6144;                   // [128] sq_j for current tile
    float* MV  = lds;                          // [256][9] merge overlay
    int*   MJ  = (int*)(lds + 2304);           // [256][9]

    const int b  = blockIdx.z;
    const int i0 = blockIdx.y * 64;
    const int js = blockIdx.x;                 // 0..15, cols js*256 .. +255
    const int tid = threadIdx.x;
    const int tx = tid & 15, ty = tid >> 4;    // frag: rows ty*4.., cols tx*4 / 64+tx*4
    const int sr = tid >> 2, g = tid & 3;      // scan: row owner, col-group

    const float sqi = sqv[b * 4096 + i0 + sr];
    float sv[9]; int sj[9];
#pragma unroll
    for (int k = 0; k < 9; ++k) { sv[k] = -FLT_MAX; sj[k] = 0x7fffffff; }

    // staging maps (16B lane stride -> 2-way banks = free; coalesced global)
    const int acl = tid >> 4, aj4 = (tid & 15) * 4;   // As: 2 rows/thread
    const int bcl = tid >> 5, bj4 = (tid & 31) * 4;   // Bs: 4 rows/thread

    for (int t = 0; t < 2; ++t) {              // 2 j-tiles of 128 cols
        const int jt = js * 256 + t * 128;
        float acc[4][8];
#pragma unroll
        for (int i = 0; i < 4; ++i)
#pragma unroll
            for (int j = 0; j < 8; ++j) acc[i][j] = 0.f;

        for (int ch = 0; ch < 4; ++ch) {       // K chunks: c = ch*32 .. +31
            __syncthreads();                   // prev readers of As/Bs/Sf done
            {
                const size_t gbase = ((size_t)(b * 128 + ch * 32)) * 4096;
                *(float4*)&As[acl * 64 + aj4] =
                    *(const float4*)&xn[gbase + (size_t)acl * 4096 + i0 + aj4];
                *(float4*)&As[(acl + 16) * 64 + aj4] =
                    *(const float4*)&xn[gbase + (size_t)(acl + 16) * 4096 + i0 + aj4];
#pragma unroll
                for (int u = 0; u < 4; ++u)
                    *(float4*)&Bs[(bcl + u * 8) * 128 + bj4] =
                        *(const float4*)&xn[gbase + (size_t)(bcl + u * 8) * 4096 + jt + bj4];
            }
            __syncthreads();
#pragma unroll
            for (int c = 0; c < 32; ++c) {
                const float4 av  = *(const float4*)&As[c * 64 + ty * 4];
                const float4 b0v = *(const float4*)&Bs[c * 128 + tx * 4];
                const float4 b1v = *(const float4*)&Bs[c * 128 + 64 + tx * 4];
                const float ar[4] = {av.x, av.y, av.z, av.w};
                const float br[8] = {b0v.x, b0v.y, b0v.z, b0v.w,
                                     b1v.x, b1v.y, b1v.z, b1v.w};
#pragma unroll
                for (int i = 0; i < 4; ++i)
#pragma unroll
                    for (int j = 0; j < 8; ++j) acc[i][j] = fmaf(ar[i], br[j], acc[i][j]);
            }
        }
        __syncthreads();                       // all FMA done; overlay Sf on As/Bs
        if (tid < 32)
            *(float4*)&SQJ[tid * 4] = *(const float4*)&sqv[b * 4096 + jt + tid * 4];

#pragma unroll
        for (int h = 0; h < 2; ++h) {          // score rows h*32..h*32+31
            if ((ty >> 3) == h) {
                const int lr = (ty & 7) * 4;
#pragma unroll
                for (int i = 0; i < 4; ++i) {
                    *(float4*)&Sf[(lr + i) * 132 + tx * 4] =
                        make_float4(acc[i][0], acc[i][1], acc[i][2], acc[i][3]);
                    *(float4*)&Sf[(lr + i) * 132 + 64 + tx * 4] =
                        make_float4(acc[i][4], acc[i][5], acc[i][6], acc[i][7]);
                }
            }
            __syncthreads();                   // scores (+SQJ) visible
            if ((sr >> 5) == h) {
                const float* row = &Sf[(sr & 31) * 132];
#pragma unroll 8
                for (int m = 0; m < 32; ++m) {
                    const int jl = m * 4 + g;  // 2-way banks in scan
                    const float full = (2.0f * row[jl] - sqi) - SQJ[jl];
                    topk_insert(sv, sj, full, jt + jl);
                }
            }
            if (h == 0) __syncthreads();       // scan(h0) done before write(h1)
        }
        // last scan protected by next tile's first barrier / merge barrier
    }
    __syncthreads();
    // in-block merge: 4 col-group lists per row -> 1 list, write split js
#pragma unroll
    for (int k = 0; k < 9; ++k) { MV[tid * 9 + k] = sv[k]; MJ[tid * 9 + k] = sj[k]; }
    __syncthreads();
    if (tid < 64) {
        float mv[9]; int mj[9];
#pragma unroll
        for (int k = 0; k < 9; ++k) { mv[k] = -FLT_MAX; mj[k] = 0x7fffffff; }
        for (int q2 = 0; q2 < 4; ++q2)
            for (int k = 0; k < 9; ++k)
                topk_insert(mv, mj, MV[(tid * 4 + q2) * 9 + k], MJ[(tid * 4 + q2) * 9 + k]);
        const int base = ((b * 4096 + i0 + tid) * NSPLIT + js) * 9;
#pragma unroll
        for (int k = 0; k < 9; ++k) { pv[base + k] = mv[k]; pj[base + k] = mj[k]; }
    }
}

// ---- Kernel M: merge 16 split-lists -> final 9 indices per row ----
__global__ __launch_bounds__(256) void merge_kernel(const float* __restrict__ pv,
                                                    const int* __restrict__ pj,
                                                    int* __restrict__ nn) {
    int t = blockIdx.x * 256 + threadIdx.x;   // 0..8191 = b*4096+n
    float sv[9]; int sj[9];
#pragma unroll
    for (int k = 0; k < 9; ++k) { sv[k] = -FLT_MAX; sj[k] = 0x7fffffff; }
    int base = t * (NSPLIT * 9);
    for (int s = 0; s < NSPLIT * 9; ++s) topk_insert(sv, sj, pv[base + s], pj[base + s]);
#pragma unroll
    for (int k = 0; k < 9; ++k) nn[t * 9 + k] = sj[k];
}

// ---- Kernel C: P/Q GEMM. o' = o0+tx*4+j over 512 packed outputs.
// P (o'<256): out[b][o'][n] layout, float4 along n. Q (o'>=256): q[b][n][o'-256].
__global__ __launch_bounds__(256, 2) void pq_kernel(const float* __restrict__ xn,
                                                    const float* __restrict__ wt,
                                                    const float* __restrict__ rnv,
                                                    float* __restrict__ q,
                                                    float* __restrict__ out) {
    __shared__ float Xs[128][64];
    __shared__ float Ws[128][64];
    const int b = blockIdx.z;
    const int n0 = blockIdx.x * 64;
    const int o0 = blockIdx.y * 64;
    const int tid = threadIdx.x;
    {
        const int c4 = tid >> 4, j4 = (tid & 15) * 4;
#pragma unroll
        for (int cc = 0; cc < 8; ++cc) {
            int c = cc * 16 + c4;
            *(float4*)&Xs[c][j4] = *(const float4*)&xn[((size_t)(b * 128 + c)) * 4096 + n0 + j4];
            *(float4*)&Ws[c][j4] = *(const float4*)&wt[c * 512 + o0 + j4];
        }
    }
    __syncthreads();
    const int tx = tid & 15, ty = tid >> 4;
    float acc[4][4];
#pragma unroll
    for (int i = 0; i < 4; ++i)
#pragma unroll
        for (int j = 0; j < 4; ++j) acc[i][j] = 0.f;
#pragma unroll 4
    for (int c = 0; c < 128; ++c) {
        const float4 av = *(const float4*)&Xs[c][ty * 4];
        const float4 bv = *(const float4*)&Ws[c][tx * 4];
        const float ar[4] = {av.x, av.y, av.z, av.w};
        const float br[4] = {bv.x, bv.y, bv.z, bv.w};
#pragma unroll
        for (int i = 0; i < 4; ++i)
#pragma unroll
            for (int j = 0; j < 4; ++j) acc[i][j] = fmaf(ar[i], br[j], acc[i][j]);
    }
    const float4 rv = *(const float4*)&rnv[b * 4096 + n0 + ty * 4];
    if (o0 < 256) {
        // P -> d_out[b][o][n], contiguous along n within each thread
#pragma unroll
        for (int j = 0; j < 4; ++j) {
            float4 v = make_float4(acc[0][j] * rv.x, acc[1][j] * rv.y,
                                   acc[2][j] * rv.z, acc[3][j] * rv.w);
            *(float4*)&out[((size_t)(b * 256 + o0 + tx * 4 + j)) * 4096 + n0 + ty * 4] = v;
        }
    } else {
        const float rr[4] = {rv.x, rv.y, rv.z, rv.w};
#pragma unroll
        for (int i = 0; i < 4; ++i) {
            float4 v = make_float4(acc[i][0] * rr[i], acc[i][1] * rr[i],
                                   acc[i][2] * rr[i], acc[i][3] * rr[i]);
            *(float4*)&q[((size_t)(b * 4096 + n0 + ty * 4 + i)) * 256 + (o0 - 256) + tx * 4] = v;
        }
    }
}

// ---- Kernel D: out[b][o][n] = relu(P(out) + bias[o] + max_k Q[nn(n,k)][o]) in place ----
__global__ __launch_bounds__(256) void gather_kernel(const float* __restrict__ q,
                                                     const int* __restrict__ nn,
                                                     const float* __restrict__ bias,
                                                     float* __restrict__ out) {
    __shared__ int idx[32][9];
    const int b = blockIdx.y, n0 = blockIdx.x * 32;
    const int tid = threadIdx.x;
    for (int t = tid; t < 288; t += 256) {
        int pt = t / 9, k = t - pt * 9;
        idx[pt][k] = nn[(b * 4096 + n0 + pt) * 9 + k];
    }
    __syncthreads();
    const float bv = bias[tid];
    const size_t orow = ((size_t)(b * 256 + tid)) * 4096 + n0;
    float pvals[32];
#pragma unroll
    for (int u = 0; u < 8; ++u)
        *(float4*)&pvals[u * 4] = *(const float4*)&out[orow + u * 4];
    float val[32];
#pragma unroll
    for (int pt = 0; pt < 32; ++pt) {
        float m = -FLT_MAX;
#pragma unroll
        for (int k = 0; k < 9; ++k) {
            int j = idx[pt][k] & 4095;             // clamp: wild index -> wrong value, not fault
            m = fmaxf(m, q[((size_t)(b * 4096 + j)) * 256 + tid]);
        }
        float vv = pvals[pt] + bv + m;
        val[pt] = vv > 0.f ? vv : 0.f;
    }
#pragma unroll
    for (int u = 0; u < 8; ++u) {
        float4 v = make_float4(val[u * 4], val[u * 4 + 1], val[u * 4 + 2], val[u * 4 + 3]);
        *(float4*)&out[orow + u * 4] = v;
    }
}

extern "C" void kernel_launch(void* const* d_in, const int* in_sizes, int n_in,
                              void* d_out, int out_size, void* d_ws, size_t ws_size,
                              hipStream_t stream) {
    const float* x    = (const float*)d_in[0];
    const float* w    = (const float*)d_in[1];
    const float* bias = (const float*)d_in[2];
    float* ws = (float*)d_ws;
    float* xn = ws + OFF_XN;
    float* sq = ws + OFF_SQ;
    float* rn = ws + OFF_RN;
    float* wt = ws + OFF_WT;
    float* q  = ws + OFF_Q;
    float* pv = ws + OFF_PV;
    int*   pj = (int*)(ws + OFF_PJ);
    int*   nn = (int*)(ws + OFF_NN);
    float* out = (float*)d_out;

    prep_kernel  <<<dim3(64, 2),     256, 0, stream>>>(x, xn, sq, rn);
    wprep_kernel <<<dim3(256),       256, 0, stream>>>(w, wt);
    knn_kernel   <<<dim3(16, 64, 2), 256, 0, stream>>>(xn, sq, pv, pj);
    merge_kernel <<<dim3(32),        256, 0, stream>>>(pv, pj, nn);
    pq_kernel    <<<dim3(64, 8, 2),  256, 0, stream>>>(xn, wt, rn, q, out);
    gather_kernel<<<dim3(128, 2),    256, 0, stream>>>(q, nn, bias, out);
}

// Round 10
// 347.134 us; speedup vs baseline: 1.1597x; 1.1597x over previous
//
#include <hip/hip_runtime.h>
#include <float.h>

// Problem constants: x (2,128,64,64) fp32, w (256,256) fp32, b (256,) fp32
// out (2,256,64,64) fp32. K=9 nearest neighbors on normalized features.
constexpr int CB = 2;      // batch
constexpr int CC = 128;    // channels
constexpr int CN = 4096;   // points (64*64)
constexpr int CO2 = 512;   // P(256) + Q(256) packed weight columns
constexpr int NSPLIT = 8;  // knn col-splits

// ---- workspace layout (float offsets) ----
// bf16x3 planes (6MB) OVERLAY the Q region (8MB): planes are consumed by
// knn_kernel BEFORE pq_kernel writes Q (same stream, serialized).
constexpr size_t OFF_XN = 0;                                  // [B][C][N] normalized x (fp32)
constexpr size_t OFF_SQ = OFF_XN + (size_t)CB * CC * CN;      // [B][N] sum(xn^2)
constexpr size_t OFF_RN = OFF_SQ + (size_t)CB * CN;           // [B][N] norm
constexpr size_t OFF_WT = OFF_RN + (size_t)CB * CN;           // [C][512] (W1-W2 | W2)^T
constexpr size_t OFF_Q  = OFF_WT + (size_t)CC * CO2;          // [B][N][256] Q (fp32)
constexpr size_t OFF_PV = OFF_Q  + (size_t)CB * CN * 256;     // [B][N][8][9] vals
constexpr size_t OFF_PJ = OFF_PV + (size_t)CB * CN * 72;      // [B][N][8][9] idx
constexpr size_t OFF_NN = OFF_PJ + (size_t)CB * CN * 72;      // [B][N][9] final idx

typedef __attribute__((ext_vector_type(8))) short bf16x8;
typedef __attribute__((ext_vector_type(4))) float f32x4;

__device__ __forceinline__ unsigned short f2bf(float f) {
    unsigned int u = __float_as_uint(f);
    unsigned int r = (u + 0x7FFFu + ((u >> 16) & 1u)) >> 16;   // round-nearest-even
    return (unsigned short)r;
}
__device__ __forceinline__ float bf2f(unsigned short h) {
    return __uint_as_float(((unsigned int)h) << 16);
}

// top-9 sorted-desc insert; comparator matches jax.lax.top_k tie-break.
__device__ __forceinline__ void topk_insert(float (&sv)[9], int (&sj)[9], float v, int jg) {
    if ((v > sv[8]) || (v == sv[8] && jg < sj[8])) {
        bool bb[9];
#pragma unroll
        for (int k = 0; k < 9; ++k) bb[k] = (v > sv[k]) || (v == sv[k] && jg < sj[k]);
#pragma unroll
        for (int k = 8; k >= 1; --k) {
            sv[k] = bb[k - 1] ? sv[k - 1] : (bb[k] ? v : sv[k]);
            sj[k] = bb[k - 1] ? sj[k - 1] : (bb[k] ? jg : sj[k]);
        }
        sv[0] = bb[0] ? v : sv[0];
        sj[0] = bb[0] ? jg : sj[0];
    }
}

// ---- Kernel A: normalize + emit bf16x3 TRANSPOSED planes x{h,m,l}T[b][n][c] ----
__global__ __launch_bounds__(256) void prep_kernel(const float* __restrict__ x,
                                                   float* __restrict__ xn,
                                                   float* __restrict__ sqv,
                                                   float* __restrict__ rnv,
                                                   unsigned short* __restrict__ xh,
                                                   unsigned short* __restrict__ xm,
                                                   unsigned short* __restrict__ xl) {
    __shared__ float XT[128][65];              // +1 pad: column reads conflict-free
    __shared__ float red[4][64];
    __shared__ float invl[64];
    const int b = blockIdx.y, n0 = blockIdx.x * 64;
    const int tid = threadIdx.x;
    const int nl = tid & 63, c0 = tid >> 6;
#pragma unroll 4
    for (int cc = 0; cc < 32; ++cc) {
        int c = cc * 4 + c0;
        XT[c][nl] = x[((size_t)(b * 128 + c)) * 4096 + n0 + nl];
    }
    __syncthreads();
    {
        float acc = 0.f;
#pragma unroll 4
        for (int cc = 0; cc < 32; ++cc) { float v = XT[c0 * 32 + cc][nl]; acc += v * v; }
        red[c0][nl] = acc;
    }
    __syncthreads();
    if (tid < 64) {
        float ss = red[0][tid] + red[1][tid] + red[2][tid] + red[3][tid] + 1e-12f;
        float sr = sqrtf(ss);
        invl[tid] = 1.0f / sr;
        rnv[b * 4096 + n0 + tid] = sr;
    }
    __syncthreads();
    {
        float acc = 0.f;
        float iv = invl[nl];
#pragma unroll 4
        for (int cc = 0; cc < 32; ++cc) {
            int c = cc * 4 + c0;
            float v = XT[c][nl] * iv;
            xn[((size_t)(b * 128 + c)) * 4096 + n0 + nl] = v;
            XT[c][nl] = v;                     // keep normalized value for pass 3
            acc += v * v;
        }
        red[c0][nl] = acc;
    }
    __syncthreads();
    if (tid < 64) {
        sqv[b * 4096 + n0 + tid] = red[0][tid] + red[1][tid] + red[2][tid] + red[3][tid];
    }
    __syncthreads();
    // pass 3: bf16x3 split, transposed [n][c] layout
    {
        const int n = tid & 63, cq = tid >> 6;     // thread: one n, 32 c's
        unsigned short hs[32], ms[32], ls[32];
#pragma unroll
        for (int cc = 0; cc < 32; ++cc) {
            float v = XT[cq * 32 + cc][n];
            unsigned short h = f2bf(v);  float hf = bf2f(h);
            float r1 = v - hf;
            unsigned short m = f2bf(r1); float mf = bf2f(m);
            unsigned short l = f2bf(r1 - mf);
            hs[cc] = h; ms[cc] = m; ls[cc] = l;
        }
        const size_t base = ((size_t)(b * 4096 + n0 + n)) * 128 + cq * 32;
#pragma unroll
        for (int q2 = 0; q2 < 4; ++q2) {
            *(float4*)&xh[base + q2 * 8] = *(const float4*)&hs[q2 * 8];
            *(float4*)&xm[base + q2 * 8] = *(const float4*)&ms[q2 * 8];
            *(float4*)&xl[base + q2 * 8] = *(const float4*)&ls[q2 * 8];
        }
    }
}

// ---- Kernel W: WT[c][o] = (o<256) ? w[o][c]-w[o][128+c] : w[o-256][128+c] ----
__global__ __launch_bounds__(256) void wprep_kernel(const float* __restrict__ w,
                                                    float* __restrict__ wt) {
    int id = blockIdx.x * 256 + threadIdx.x;   // 65536 = 128*512
    int c = id >> 9, o = id & 511;
    float v;
    if (o < 256) v = w[o * 256 + c] - w[o * 256 + 128 + c];
    else         v = w[(o - 256) * 256 + 128 + c];
    wt[c * 512 + o] = v;
}

// ---- Kernel B v10: MFMA bf16x3-split Gram + top-9 ----
// v9 with the LDS overflow fixed: merge overlay MV[256][9]+MJ[256][9] needs
// 4608 floats; v9 declared 4416 -> MJ writes past the allocation corrupted
// rows 58-63 of every block (r9 absmax 3.14). ONLY the lds size changed.
// inner = hh + hm + mh + mm + hl + lh; error ~3e-8 < fp32 reorder noise.
// Frags straight from global x*T[n][c]; no LDS, no barriers in the K-loop.
// C/D layout (m89-verified): col = lane&15, row = (lane>>4)*4 + reg.
// FALLBACK if absmax is still O(1): swap mfma operands + transpose Sf write.
__global__ __launch_bounds__(256, 2) void knn_kernel(const unsigned short* __restrict__ xh,
                                                     const unsigned short* __restrict__ xm,
                                                     const unsigned short* __restrict__ xl,
                                                     const float* __restrict__ sqv,
                                                     float* __restrict__ pv,
                                                     int* __restrict__ pj) {
    __shared__ float lds[4608];                // 18,432 B (merge overlay needs 4608)
    float* Sf  = lds;                          // [64][68] scores (4352 f)
    float* SQJ = lds + 4352;                   // [64]
    float* MV  = lds;                          // [256][9] merge overlay (2304 f)
    int*   MJ  = (int*)(lds + 2304);           // [256][9] (floats 2304..4607)

    const int b  = blockIdx.z;
    const int i0 = blockIdx.y * 64;
    const int js = blockIdx.x;                 // cols js*512 .. +511
    const int tid = threadIdx.x;
    const int lane = tid & 63, w = tid >> 6;
    const int wi = w >> 1, wj = w & 1;         // wave quadrant
    const int l15 = lane & 15, l4 = lane >> 4;
    const int sr = tid >> 2, g = tid & 3;      // scan: row owner, col-group

    const size_t arow0 = ((size_t)(b * 4096 + i0 + wi * 32 + l15)) * 128;  // mt=0
    const size_t arow1 = arow0 + 16 * 128;                                  // mt=1
    const float sqi = sqv[b * 4096 + i0 + sr];
    float sv[9]; int sj[9];
#pragma unroll
    for (int k = 0; k < 9; ++k) { sv[k] = -FLT_MAX; sj[k] = 0x7fffffff; }

    for (int t = 0; t < 8; ++t) {
        const int jt = js * 512 + t * 64;
        const size_t brow0 = ((size_t)(b * 4096 + jt + wj * 32 + l15)) * 128;
        const size_t brow1 = brow0 + 16 * 128;
        f32x4 c00 = {0.f, 0.f, 0.f, 0.f}, c01 = c00, c10 = c00, c11 = c00;

#pragma unroll
        for (int ch = 0; ch < 4; ++ch) {       // K chunks of 32, no barriers
            const size_t ko = ch * 32 + l4 * 8;
            bf16x8 ah0 = *(const bf16x8*)(xh + arow0 + ko);
            bf16x8 ah1 = *(const bf16x8*)(xh + arow1 + ko);
            bf16x8 bh0 = *(const bf16x8*)(xh + brow0 + ko);
            bf16x8 bh1 = *(const bf16x8*)(xh + brow1 + ko);
            bf16x8 as_ = *(const bf16x8*)(xm + arow0 + ko);
            bf16x8 as1 = *(const bf16x8*)(xm + arow1 + ko);
            bf16x8 bs_ = *(const bf16x8*)(xm + brow0 + ko);
            bf16x8 bs1 = *(const bf16x8*)(xm + brow1 + ko);
            // hh
            c00 = __builtin_amdgcn_mfma_f32_16x16x32_bf16(ah0, bh0, c00, 0, 0, 0);
            c01 = __builtin_amdgcn_mfma_f32_16x16x32_bf16(ah0, bh1, c01, 0, 0, 0);
            c10 = __builtin_amdgcn_mfma_f32_16x16x32_bf16(ah1, bh0, c10, 0, 0, 0);
            c11 = __builtin_amdgcn_mfma_f32_16x16x32_bf16(ah1, bh1, c11, 0, 0, 0);
            // hm
            c00 = __builtin_amdgcn_mfma_f32_16x16x32_bf16(ah0, bs_, c00, 0, 0, 0);
            c01 = __builtin_amdgcn_mfma_f32_16x16x32_bf16(ah0, bs1, c01, 0, 0, 0);
            c10 = __builtin_amdgcn_mfma_f32_16x16x32_bf16(ah1, bs_, c10, 0, 0, 0);
            c11 = __builtin_amdgcn_mfma_f32_16x16x32_bf16(ah1, bs1, c11, 0, 0, 0);
            // mh
            c00 = __builtin_amdgcn_mfma_f32_16x16x32_bf16(as_, bh0, c00, 0, 0, 0);
            c01 = __builtin_amdgcn_mfma_f32_16x16x32_bf16(as_, bh1, c01, 0, 0, 0);
            c10 = __builtin_amdgcn_mfma_f32_16x16x32_bf16(as1, bh0, c10, 0, 0, 0);
            c11 = __builtin_amdgcn_mfma_f32_16x16x32_bf16(as1, bh1, c11, 0, 0, 0);
            // mm
            c00 = __builtin_amdgcn_mfma_f32_16x16x32_bf16(as_, bs_, c00, 0, 0, 0);
            c01 = __builtin_amdgcn_mfma_f32_16x16x32_bf16(as_, bs1, c01, 0, 0, 0);
            c10 = __builtin_amdgcn_mfma_f32_16x16x32_bf16(as1, bs_, c10, 0, 0, 0);
            c11 = __builtin_amdgcn_mfma_f32_16x16x32_bf16(as1, bs1, c11, 0, 0, 0);
            // reuse m-slots for l-plane
            as_ = *(const bf16x8*)(xl + arow0 + ko);
            as1 = *(const bf16x8*)(xl + arow1 + ko);
            bs_ = *(const bf16x8*)(xl + brow0 + ko);
            bs1 = *(const bf16x8*)(xl + brow1 + ko);
            // hl
            c00 = __builtin_amdgcn_mfma_f32_16x16x32_bf16(ah0, bs_, c00, 0, 0, 0);
            c01 = __builtin_amdgcn_mfma_f32_16x16x32_bf16(ah0, bs1, c01, 0, 0, 0);
            c10 = __builtin_amdgcn_mfma_f32_16x16x32_bf16(ah1, bs_, c10, 0, 0, 0);
            c11 = __builtin_amdgcn_mfma_f32_16x16x32_bf16(ah1, bs1, c11, 0, 0, 0);
            // lh
            c00 = __builtin_amdgcn_mfma_f32_16x16x32_bf16(as_, bh0, c00, 0, 0, 0);
            c01 = __builtin_amdgcn_mfma_f32_16x16x32_bf16(as_, bh1, c01, 0, 0, 0);
            c10 = __builtin_amdgcn_mfma_f32_16x16x32_bf16(as1, bh0, c10, 0, 0, 0);
            c11 = __builtin_amdgcn_mfma_f32_16x16x32_bf16(as1, bh1, c11, 0, 0, 0);
        }
        __syncthreads();                       // prev scan done before Sf overwrite
        {
            const int ib = wi * 32 + l4 * 4, jb = wj * 32 + l15;
#pragma unroll
            for (int r = 0; r < 4; ++r) {
                Sf[(ib + r) * 68 + jb]           = c00[r];
                Sf[(ib + r) * 68 + jb + 16]      = c01[r];
                Sf[(ib + 16 + r) * 68 + jb]      = c10[r];
                Sf[(ib + 16 + r) * 68 + jb + 16] = c11[r];
            }
        }
        if (tid < 16)
            *(float4*)&SQJ[tid * 4] = *(const float4*)&sqv[b * 4096 + jt + tid * 4];
        __syncthreads();                       // scores + sqj visible
#pragma unroll 8
        for (int m = 0; m < 16; ++m) {
            const int jl = m * 4 + g;
            const float full = (2.0f * Sf[sr * 68 + jl] - sqi) - SQJ[jl];
            topk_insert(sv, sj, full, jt + jl);
        }
        __syncthreads();                       // scan done before next overwrite
    }
    // in-block merge: 4 col-group lists per row -> 1 list, write split js
#pragma unroll
    for (int k = 0; k < 9; ++k) { MV[tid * 9 + k] = sv[k]; MJ[tid * 9 + k] = sj[k]; }
    __syncthreads();
    if (tid < 64) {
        float mv[9]; int mj[9];
#pragma unroll
        for (int k = 0; k < 9; ++k) { mv[k] = -FLT_MAX; mj[k] = 0x7fffffff; }
        for (int q2 = 0; q2 < 4; ++q2)
            for (int k = 0; k < 9; ++k)
                topk_insert(mv, mj, MV[(tid * 4 + q2) * 9 + k], MJ[(tid * 4 + q2) * 9 + k]);
        const int base = ((b * 4096 + i0 + tid) * NSPLIT + js) * 9;
#pragma unroll
        for (int k = 0; k < 9; ++k) { pv[base + k] = mv[k]; pj[base + k] = mj[k]; }
    }
}

// ---- Kernel M: merge 8 split-lists -> final 9 indices per row ----
__global__ __launch_bounds__(256) void merge_kernel(const float* __restrict__ pv,
                                                    const int* __restrict__ pj,
                                                    int* __restrict__ nn) {
    int t = blockIdx.x * 256 + threadIdx.x;
    float sv[9]; int sj[9];
#pragma unroll
    for (int k = 0; k < 9; ++k) { sv[k] = -FLT_MAX; sj[k] = 0x7fffffff; }
    int base = t * (NSPLIT * 9);
    for (int s = 0; s < NSPLIT * 9; ++s) topk_insert(sv, sj, pv[base + s], pj[base + s]);
#pragma unroll
    for (int k = 0; k < 9; ++k) nn[t * 9 + k] = sj[k];
}

// ---- Kernel C: P/Q GEMM (fp32, unchanged from r7) ----
__global__ __launch_bounds__(256, 2) void pq_kernel(const float* __restrict__ xn,
                                                    const float* __restrict__ wt,
                                                    const float* __restrict__ rnv,
                                                    float* __restrict__ q,
                                                    float* __restrict__ out) {
    __shared__ float Xs[128][64];
    __shared__ float Ws[128][64];
    const int b = blockIdx.z;
    const int n0 = blockIdx.x * 64;
    const int o0 = blockIdx.y * 64;
    const int tid = threadIdx.x;
    {
        const int c4 = tid >> 4, j4 = (tid & 15) * 4;
#pragma unroll
        for (int cc = 0; cc < 8; ++cc) {
            int c = cc * 16 + c4;
            *(float4*)&Xs[c][j4] = *(const float4*)&xn[((size_t)(b * 128 + c)) * 4096 + n0 + j4];
            *(float4*)&Ws[c][j4] = *(const float4*)&wt[c * 512 + o0 + j4];
        }
    }
    __syncthreads();
    const int tx = tid & 15, ty = tid >> 4;
    float acc[4][4];
#pragma unroll
    for (int i = 0; i < 4; ++i)
#pragma unroll
        for (int j = 0; j < 4; ++j) acc[i][j] = 0.f;
#pragma unroll 4
    for (int c = 0; c < 128; ++c) {
        const float4 av = *(const float4*)&Xs[c][ty * 4];
        const float4 bv = *(const float4*)&Ws[c][tx * 4];
        const float ar[4] = {av.x, av.y, av.z, av.w};
        const float br[4] = {bv.x, bv.y, bv.z, bv.w};
#pragma unroll
        for (int i = 0; i < 4; ++i)
#pragma unroll
            for (int j = 0; j < 4; ++j) acc[i][j] = fmaf(ar[i], br[j], acc[i][j]);
    }
    const float4 rv = *(const float4*)&rnv[b * 4096 + n0 + ty * 4];
    if (o0 < 256) {
#pragma unroll
        for (int j = 0; j < 4; ++j) {
            float4 v = make_float4(acc[0][j] * rv.x, acc[1][j] * rv.y,
                                   acc[2][j] * rv.z, acc[3][j] * rv.w);
            *(float4*)&out[((size_t)(b * 256 + o0 + tx * 4 + j)) * 4096 + n0 + ty * 4] = v;
        }
    } else {
        const float rr[4] = {rv.x, rv.y, rv.z, rv.w};
#pragma unroll
        for (int i = 0; i < 4; ++i) {
            float4 v = make_float4(acc[i][0] * rr[i], acc[i][1] * rr[i],
                                   acc[i][2] * rr[i], acc[i][3] * rr[i]);
            *(float4*)&q[((size_t)(b * 4096 + n0 + ty * 4 + i)) * 256 + (o0 - 256) + tx * 4] = v;
        }
    }
}

// ---- Kernel D: out = relu(P(out) + bias + max_k Q[nn]) in place (unchanged) ----
__global__ __launch_bounds__(256) void gather_kernel(const float* __restrict__ q,
                                                     const int* __restrict__ nn,
                                                     const float* __restrict__ bias,
                                                     float* __restrict__ out) {
    __shared__ int idx[32][9];
    const int b = blockIdx.y, n0 = blockIdx.x * 32;
    const int tid = threadIdx.x;
    for (int t = tid; t < 288; t += 256) {
        int pt = t / 9, k = t - pt * 9;
        idx[pt][k] = nn[(b * 4096 + n0 + pt) * 9 + k];
    }
    __syncthreads();
    const float bv = bias[tid];
    const size_t orow = ((size_t)(b * 256 + tid)) * 4096 + n0;
    float pvals[32];
#pragma unroll
    for (int u = 0; u < 8; ++u)
        *(float4*)&pvals[u * 4] = *(const float4*)&out[orow + u * 4];
    float val[32];
#pragma unroll
    for (int pt = 0; pt < 32; ++pt) {
        float m = -FLT_MAX;
#pragma unroll
        for (int k = 0; k < 9; ++k) {
            int j = idx[pt][k] & 4095;
            m = fmaxf(m, q[((size_t)(b * 4096 + j)) * 256 + tid]);
        }
        float vv = pvals[pt] + bv + m;
        val[pt] = vv > 0.f ? vv : 0.f;
    }
#pragma unroll
    for (int u = 0; u < 8; ++u) {
        float4 v = make_float4(val[u * 4], val[u * 4 + 1], val[u * 4 + 2], val[u * 4 + 3]);
        *(float4*)&out[orow + u * 4] = v;
    }
}

extern "C" void kernel_launch(void* const* d_in, const int* in_sizes, int n_in,
                              void* d_out, int out_size, void* d_ws, size_t ws_size,
                              hipStream_t stream) {
    const float* x    = (const float*)d_in[0];
    const float* w    = (const float*)d_in[1];
    const float* bias = (const float*)d_in[2];
    float* ws = (float*)d_ws;
    float* xn = ws + OFF_XN;
    float* sq = ws + OFF_SQ;
    float* rn = ws + OFF_RN;
    float* wt = ws + OFF_WT;
    float* q  = ws + OFF_Q;
    unsigned short* xh = (unsigned short*)(ws + OFF_Q);        // planes overlay Q
    unsigned short* xm = xh + (size_t)CB * CN * CC;
    unsigned short* xl = xm + (size_t)CB * CN * CC;
    float* pv = ws + OFF_PV;
    int*   pj = (int*)(ws + OFF_PJ);
    int*   nn = (int*)(ws + OFF_NN);
    float* out = (float*)d_out;

    prep_kernel  <<<dim3(64, 2),    256, 0, stream>>>(x, xn, sq, rn, xh, xm, xl);
    wprep_kernel <<<dim3(256),      256, 0, stream>>>(w, wt);
    knn_kernel   <<<dim3(8, 64, 2), 256, 0, stream>>>(xh, xm, xl, sq, pv, pj);
    merge_kernel <<<dim3(32),       256, 0, stream>>>(pv, pj, nn);
    pq_kernel    <<<dim3(64, 8, 2), 256, 0, stream>>>(xn, wt, rn, q, out);
    gather_kernel<<<dim3(128, 2),   256, 0, stream>>>(q, nn, bias, out);
}